// Round 4
// baseline (2047.184 us; speedup 1.0000x reference)
//
#include <hip/hip_runtime.h>

#define TT 2048
#define BB 256
#define FF 64
#define HH 128
#define NT 768   // 12 waves: waves 0-3 -> r cols, 4-7 -> z cols, 8-11 -> n cols
                 // within a wave: lanes 0-31 = k-half 0, lanes 32-63 = k-half 1

// Grid is 256 blocks = 1 block/CU = 12 waves/CU = 3 waves/EU, period.
// Round-2/3 showed the compiler targeting 6 waves/EU (VGPR=84) and demoting
// the 96 stationary weight floats to reload-per-iteration. Clamp the
// occupancy target to the truth so the weights stay resident.
__global__ void __launch_bounds__(NT)
__attribute__((amdgpu_waves_per_eu(3, 3)))
gru_scan_kernel(
    const float* __restrict__ x,     // [T,B,F]
    const float* __restrict__ Wi,    // [F,3H] packed r|z|n
    const float* __restrict__ bi,    // [3H]
    const float* __restrict__ Whrz,  // [H,2H] packed r|z
    const float* __restrict__ Whn,   // [H,H]
    const float* __restrict__ bn,    // [H]
    float* __restrict__ out)         // [T,B,H]
{
  const int b    = blockIdx.x;
  const int tid  = threadIdx.x;
  const int w    = tid >> 6;       // wave 0..11
  const int lane = tid & 63;
  const int half = lane >> 5;      // k-half 0/1
  const int sub  = lane & 31;
  const int j    = w * 32 + sub;   // output column 0..383

  __shared__ __align__(16) float h_lds[HH];
  __shared__ __align__(16) float x_lds[2][FF];
  __shared__ __align__(16) float pre_z[HH];
  __shared__ __align__(16) float pre_hn[HH];
  __shared__ __align__(16) float pre_xin[HH];

  // ---- stationary weights: 32 + 64 floats per thread ----
  float wi[FF / 2];
  float wh[HH / 2];
  const int kx0 = half * (FF / 2);
  const int kh0 = half * (HH / 2);
  #pragma unroll
  for (int k = 0; k < FF / 2; ++k) wi[k] = Wi[(size_t)(kx0 + k) * 384 + j];
  if (j < 256) {
    #pragma unroll
    for (int k = 0; k < HH / 2; ++k) wh[k] = Whrz[(size_t)(kh0 + k) * 256 + j];
  } else {
    #pragma unroll
    for (int k = 0; k < HH / 2; ++k) wh[k] = Whn[(size_t)(kh0 + k) * 128 + (j - 256)];
  }

  // biases folded into half-0 accumulator init
  const float bias_i = (half == 0) ? bi[j] : 0.0f;
  const float bias_h = (half == 0 && j >= 256) ? bn[j - 256] : 0.0f;

  // ---- init h = 0, stage x[t=0] ----
  if (tid < HH) h_lds[tid] = 0.0f;
  if (tid < FF / 4) {
    ((float4*)x_lds[0])[tid] = ((const float4*)(x + (size_t)b * FF))[tid];
  }
  float h_old = 0.0f;   // owned by (j<128, half==0) threads
  float r_reg = 0.0f;

  const bool loader = (tid >= NT - 16);   // wave 11, lanes 48-63
  const int  lidx   = tid - (NT - 16);
  const float4* xsrc = (const float4*)(x + (size_t)BB * FF + (size_t)b * FF) + lidx;
  float* outp = out + (size_t)b * HH + (j & 127);   // valid use only when j<128
  __syncthreads();

  const float* xbuf_cur = &x_lds[0][kx0];
  const float* xbuf_nxt = &x_lds[1][kx0];
  float* xw_cur = &x_lds[0][0];
  float* xw_nxt = &x_lds[1][0];

  for (int t = 0; t < TT; ++t) {
    // issue next-x prefetch early (consumed after barrier1)
    float4 xnext;
    if (loader && t + 1 < TT) {
      xnext = *xsrc;
      xsrc += (BB * FF) / 4;
    }

    // ---- input dot: 32 MACs over k in [kx0, kx0+32) ----
    const float4* xc = (const float4*)xbuf_cur;
    float ai0 = bias_i, ai1 = 0.f, ai2 = 0.f, ai3 = 0.f;
    #pragma unroll
    for (int kk = 0; kk < FF / 8; ++kk) {
      float4 v = xc[kk];
      ai0 += v.x * wi[4 * kk + 0];
      ai1 += v.y * wi[4 * kk + 1];
      ai2 += v.z * wi[4 * kk + 2];
      ai3 += v.w * wi[4 * kk + 3];
    }
    float acc_i = (ai0 + ai1) + (ai2 + ai3);

    // ---- recurrent dot: 64 MACs over k in [kh0, kh0+64) ----
    const float4* hc = (const float4*)&h_lds[kh0];
    float ah0 = bias_h, ah1 = 0.f, ah2 = 0.f, ah3 = 0.f;
    #pragma unroll
    for (int kk = 0; kk < HH / 8; ++kk) {
      float4 v = hc[kk];
      ah0 += v.x * wh[4 * kk + 0];
      ah1 += v.y * wh[4 * kk + 1];
      ah2 += v.z * wh[4 * kk + 2];
      ah3 += v.w * wh[4 * kk + 3];
    }
    float acc_h = (ah0 + ah1) + (ah2 + ah3);

    // ---- cross-half reduce + gates (wave-uniform branches) ----
    if (j < 256) {
      float s = acc_i + acc_h;
      s += __shfl_xor(s, 32);
      float g = 1.0f / (1.0f + __expf(-s));
      if (j < 128) {
        r_reg = g;                         // r stays in-register
      } else if (half == 0) {
        pre_z[j - 128] = g;                // z
      }
    } else {
      float ti = acc_i + __shfl_xor(acc_i, 32);
      float th = acc_h + __shfl_xor(acc_h, 32);
      if (half == 0) {
        pre_hn[j - 256]  = th;             // h@Whn + bn
        pre_xin[j - 256] = ti;             // x@Win + bi_n
      }
    }
    __syncthreads();

    // ---- combine: 128 threads (r-cols, half 0) ----
    if (j < 128 && half == 0) {
      const float z   = pre_z[j];
      const float hn  = pre_hn[j];
      const float xin = pre_xin[j];
      const float narg = xin + r_reg * hn;
      const float n = 1.0f - 2.0f / (__expf(2.0f * narg) + 1.0f);
      const float hnew = z * (h_old - n) + n;   // (1-z)*n + z*h
      h_old = hnew;
      h_lds[j] = hnew;
      *outp = hnew;
      outp += BB * HH;
    }
    if (loader && t + 1 < TT) {
      ((float4*)xw_nxt)[lidx] = xnext;
    }
    { const float* tmp = xbuf_cur; xbuf_cur = xbuf_nxt; xbuf_nxt = tmp; }
    { float* tmp = xw_cur; xw_cur = xw_nxt; xw_nxt = tmp; }
    __syncthreads();
  }
}

extern "C" void kernel_launch(void* const* d_in, const int* in_sizes, int n_in,
                              void* d_out, int out_size, void* d_ws, size_t ws_size,
                              hipStream_t stream) {
  const float* x    = (const float*)d_in[0];
  const float* Wi   = (const float*)d_in[1];
  const float* bi   = (const float*)d_in[2];
  const float* Whrz = (const float*)d_in[3];
  const float* Whn  = (const float*)d_in[4];
  const float* bn   = (const float*)d_in[5];
  float* out = (float*)d_out;

  gru_scan_kernel<<<dim3(BB), dim3(NT), 0, stream>>>(
      x, Wi, bi, Whrz, Whn, bn, out);
}

// Round 5
// 1909.791 us; speedup vs baseline: 1.0719x; 1.0719x over previous
//
#include <hip/hip_runtime.h>

#define TT 2048
#define BB 256
#define FF 64
#define HH 128
#define NT 512   // 128 quads: quad g computes r[g], z[g], n[g]; lane q = k-quarter

// LDS-BW analysis (round 4): old layout streamed 294 KB/step through LDS
// (2304 cyc = the whole step time). This layout reads ~6 KB/step unique:
// one ds_read_b128 feeds 12 FMAs, quads broadcast across g, k-chunks
// staggered by q so the 4 distinct addresses hit disjoint banks.
__global__ void __launch_bounds__(NT)
__attribute__((amdgpu_waves_per_eu(2, 2)))
gru_scan_kernel(const float* __restrict__ x,     // [T,B,F]
                const float* __restrict__ Wi,    // [F,3H] r|z|n
                const float* __restrict__ bi,    // [3H]
                const float* __restrict__ Whrz,  // [H,2H] r|z
                const float* __restrict__ Whn,   // [H,H]
                const float* __restrict__ bn,    // [H]
                float* __restrict__ out)         // [T,B,H]
{
  const int b   = blockIdx.x;
  const int tid = threadIdx.x;
  const int q   = tid & 3;    // k-quarter 0..3
  const int g   = tid >> 2;   // hidden unit 0..127

  __shared__ __align__(16) float h_lds[2][HH];
  __shared__ __align__(16) float x_lds[2][FF];

  // staggered k-chunk schedule (float offsets, constant per thread)
  int xoff[4];
  int hoff[8];
  #pragma unroll
  for (int i = 0; i < 4; ++i) xoff[i] = 16 * q + 4 * ((i + q) & 3);
  #pragma unroll
  for (int m = 0; m < 8; ++m) hoff[m] = 32 * q + 4 * ((m + 2 * q) & 7);

  // ---- stationary weights, pre-rotated to match the chunk schedule ----
  float wxr[16], wxz[16], wxn[16];
  float whr[32], whz[32], whn_[32];
  #pragma unroll
  for (int i = 0; i < 4; ++i) {
    #pragma unroll
    for (int e = 0; e < 4; ++e) {
      const int row = xoff[i] + e;                 // k index 0..63
      wxr[4 * i + e] = Wi[(size_t)row * 384 + g];
      wxz[4 * i + e] = Wi[(size_t)row * 384 + 128 + g];
      wxn[4 * i + e] = Wi[(size_t)row * 384 + 256 + g];
    }
  }
  #pragma unroll
  for (int m = 0; m < 8; ++m) {
    #pragma unroll
    for (int e = 0; e < 4; ++e) {
      const int row = hoff[m] + e;                 // k index 0..127
      whr[4 * m + e]  = Whrz[(size_t)row * 256 + g];
      whz[4 * m + e]  = Whrz[(size_t)row * 256 + 128 + g];
      whn_[4 * m + e] = Whn[(size_t)row * 128 + g];
    }
  }
  // biases added once per quad (q==0 partial)
  const float b_r  = (q == 0) ? bi[g]       : 0.0f;
  const float b_z  = (q == 0) ? bi[128 + g] : 0.0f;
  const float b_xn = (q == 0) ? bi[256 + g] : 0.0f;
  const float b_hn = (q == 0) ? bn[g]       : 0.0f;

  // ---- init: h=0, stage x[t=0] ----
  if (tid < HH) h_lds[0][tid] = 0.0f;
  if (tid < FF / 4) {
    ((float4*)x_lds[0])[tid] = ((const float4*)(x + (size_t)b * FF))[tid];
  }
  const bool is_loader = (tid < 64) && (q == 1);   // wave 0, 16 lanes
  const int  lidx      = g;                        // 0..15 for loaders
  const float4* xsrc =
      (const float4*)(x + ((size_t)BB + b) * FF) + lidx;  // x[t=1] row
  float* outp = out + (size_t)b * HH + g;
  float h_old = 0.0f;
  __syncthreads();

  for (int t = 0; t < TT; ++t) {
    // prefetch next x row into registers (lands in LDS before the barrier)
    float4 xn4;
    if (is_loader && t + 1 < TT) {
      xn4 = *xsrc;
      xsrc += (BB * FF) / 4;
    }

    const float* xb = x_lds[t & 1];
    const float* hb = h_lds[t & 1];

    float axr = b_r, axz = b_z, axn = b_xn;
    float ahr = 0.0f, ahz = 0.0f, ahn = b_hn;

    // x-dot: 16 k's -> 48 FMA
    #pragma unroll
    for (int i = 0; i < 4; ++i) {
      const float4 v = *(const float4*)(xb + xoff[i]);
      axr += v.x * wxr[4 * i + 0];
      axr += v.y * wxr[4 * i + 1];
      axr += v.z * wxr[4 * i + 2];
      axr += v.w * wxr[4 * i + 3];
      axz += v.x * wxz[4 * i + 0];
      axz += v.y * wxz[4 * i + 1];
      axz += v.z * wxz[4 * i + 2];
      axz += v.w * wxz[4 * i + 3];
      axn += v.x * wxn[4 * i + 0];
      axn += v.y * wxn[4 * i + 1];
      axn += v.z * wxn[4 * i + 2];
      axn += v.w * wxn[4 * i + 3];
    }
    // h-dot: 32 k's -> 96 FMA
    #pragma unroll
    for (int m = 0; m < 8; ++m) {
      const float4 v = *(const float4*)(hb + hoff[m]);
      ahr += v.x * whr[4 * m + 0];
      ahr += v.y * whr[4 * m + 1];
      ahr += v.z * whr[4 * m + 2];
      ahr += v.w * whr[4 * m + 3];
      ahz += v.x * whz[4 * m + 0];
      ahz += v.y * whz[4 * m + 1];
      ahz += v.z * whz[4 * m + 2];
      ahz += v.w * whz[4 * m + 3];
      ahn += v.x * whn_[4 * m + 0];
      ahn += v.y * whn_[4 * m + 1];
      ahn += v.z * whn_[4 * m + 2];
      ahn += v.w * whn_[4 * m + 3];
    }

    // quad butterfly reduce (lanes g*4+q, masks 1 and 2 stay in-quad)
    float pr = axr + ahr;
    float pz = axz + ahz;
    float xn = axn;
    float hn = ahn;
    pr += __shfl_xor(pr, 1);  pr += __shfl_xor(pr, 2);
    pz += __shfl_xor(pz, 1);  pz += __shfl_xor(pz, 2);
    xn += __shfl_xor(xn, 1);  xn += __shfl_xor(xn, 2);
    hn += __shfl_xor(hn, 1);  hn += __shfl_xor(hn, 2);

    // gates (computed redundantly by all 4 q-lanes; no divergence)
    const float r = 1.0f / (1.0f + __expf(-pr));
    const float z = 1.0f / (1.0f + __expf(-pz));
    const float na = xn + r * hn;
    const float n = 1.0f - 2.0f / (__expf(2.0f * na) + 1.0f);   // tanh
    const float hnew = z * (h_old - n) + n;                     // (1-z)n + z h
    h_old = hnew;

    if (q == 0) {
      h_lds[(t + 1) & 1][g] = hnew;   // 16 consecutive floats/wave: no conflict
      *outp = hnew;
    }
    outp += BB * HH;
    if (is_loader && t + 1 < TT) {
      *(float4*)(x_lds[(t + 1) & 1] + 4 * lidx) = xn4;
    }
    __syncthreads();   // single barrier: h and x are double-buffered
  }
}

extern "C" void kernel_launch(void* const* d_in, const int* in_sizes, int n_in,
                              void* d_out, int out_size, void* d_ws, size_t ws_size,
                              hipStream_t stream) {
  const float* x    = (const float*)d_in[0];
  const float* Wi   = (const float*)d_in[1];
  const float* bi   = (const float*)d_in[2];
  const float* Whrz = (const float*)d_in[3];
  const float* Whn  = (const float*)d_in[4];
  const float* bn   = (const float*)d_in[5];
  float* out = (float*)d_out;

  gru_scan_kernel<<<dim3(BB), dim3(NT), 0, stream>>>(
      x, Wi, bi, Whrz, Whn, bn, out);
}

// Round 6
// 1886.089 us; speedup vs baseline: 1.0854x; 1.0126x over previous
//
#include <hip/hip_runtime.h>

#define TT 2048
#define BB 256
#define FF 64
#define HH 128
#define NT 1024  // 16 waves = 4 waves/EU. Octet layout: 8 lanes per hidden unit.

// DPP quad_perm butterfly adds (pure VALU — keeps the reduction off the DS pipe)
__device__ __forceinline__ float dpp_add_xor1(float v) {
  int r = __builtin_amdgcn_update_dpp(0, __float_as_int(v), 0xB1, 0xf, 0xf, true);
  return v + __int_as_float(r);
}
__device__ __forceinline__ float dpp_add_xor2(float v) {
  int r = __builtin_amdgcn_update_dpp(0, __float_as_int(v), 0x4E, 0xf, 0xf, true);
  return v + __int_as_float(r);
}

// Latency-bound analysis (rounds 1..5): step time scaled ~1/waves. Max out
// waves (16/CU), shorten the per-step chain (DPP reduce, broadcast ds_reads),
// keep weights at 72/thread so they stay register-resident.
__global__ void __launch_bounds__(NT)
__attribute__((amdgpu_waves_per_eu(4, 4)))
gru_scan_kernel(const float* __restrict__ x,     // [T,B,F]
                const float* __restrict__ Wi,    // [F,3H] r|z|n
                const float* __restrict__ bi,    // [3H]
                const float* __restrict__ Whrz,  // [H,2H] r|z
                const float* __restrict__ Whn,   // [H,H]
                const float* __restrict__ bn,    // [H]
                float* __restrict__ out)         // [T,B,H]
{
  const int b    = blockIdx.x;
  const int tid  = threadIdx.x;
  const int w    = tid >> 6;         // wave 0..15
  const int lane = tid & 63;
  const int hl   = lane >> 5;        // half 0/1  -> k bit via xor32 combine
  const int pp   = (lane >> 2) & 7;  // octet id within wave
  const int q    = lane & 3;         // quad lane -> xor1/xor2 combine
  const int c    = hl * 4 + q;       // k-chunk 0..7
  const int g    = w * 8 + pp;       // hidden unit 0..127

  __shared__ __align__(16) float h_lds[2][HH];
  __shared__ __align__(16) float x_lds[2][FF];

  // Staggered chunk schedule: read slot m hits bank-quad (4c + sigma) & 7,
  // sigma chosen so the 8 distinct c-addresses cover 8 distinct bank quads.
  int hoff[4], xoff[2];
  #pragma unroll
  for (int m = 0; m < 4; ++m) hoff[m] = 16 * c + 4 * ((m + (c >> 1)) & 3);
  #pragma unroll
  for (int m = 0; m < 2; ++m) xoff[m] = 8 * c + 4 * ((m + (c >> 2)) & 1);

  // ---- stationary weights: 48 h + 24 x = 72 floats/thread ----
  float whr[16], whz[16], whn_[16];
  float wxr[8], wxz[8], wxn[8];
  #pragma unroll
  for (int m = 0; m < 4; ++m) {
    #pragma unroll
    for (int e = 0; e < 4; ++e) {
      const int k = hoff[m] + e;                    // 0..127
      whr[4 * m + e]  = Whrz[(size_t)k * 256 + g];
      whz[4 * m + e]  = Whrz[(size_t)k * 256 + 128 + g];
      whn_[4 * m + e] = Whn[(size_t)k * 128 + g];
    }
  }
  #pragma unroll
  for (int m = 0; m < 2; ++m) {
    #pragma unroll
    for (int e = 0; e < 4; ++e) {
      const int k = xoff[m] + e;                    // 0..63
      wxr[4 * m + e] = Wi[(size_t)k * 384 + g];
      wxz[4 * m + e] = Wi[(size_t)k * 384 + 128 + g];
      wxn[4 * m + e] = Wi[(size_t)k * 384 + 256 + g];
    }
  }
  const float b_r  = (c == 0) ? bi[g]       : 0.0f;
  const float b_z  = (c == 0) ? bi[128 + g] : 0.0f;
  const float b_xn = (c == 0) ? bi[256 + g] : 0.0f;
  const float b_hn = (c == 0) ? bn[g]       : 0.0f;

  // ---- init: h=0, stage x[t=0] ----
  if (tid < HH) h_lds[0][tid] = 0.0f;
  if (tid < FF / 4) {
    ((float4*)x_lds[0])[tid] = ((const float4*)(x + (size_t)b * FF))[tid];
  }
  const bool loader = (tid >= NT - 16);     // wave 15, lanes 48..63
  const int  lidx   = tid - (NT - 16);
  const float4* xsrc = (const float4*)(x + ((size_t)BB + b) * FF) + lidx;
  float* outp = out + (size_t)b * HH + g;
  float h_old = 0.0f;
  __syncthreads();

  for (int t = 0; t < TT; ++t) {
    float4 xn4;
    if (loader && t + 1 < TT) {
      xn4 = *xsrc;
      xsrc += (BB * FF) / 4;
    }

    const float* xb = x_lds[t & 1];
    const float* hb = h_lds[t & 1];

    float axr = b_r, axz = b_z, axn = b_xn;
    float ahr = 0.0f, ahz = 0.0f, ahn = b_hn;

    // x-dot: 8 k's -> 24 FMA
    #pragma unroll
    for (int m = 0; m < 2; ++m) {
      const float4 v = *(const float4*)(xb + xoff[m]);
      axr += v.x * wxr[4 * m + 0];
      axr += v.y * wxr[4 * m + 1];
      axr += v.z * wxr[4 * m + 2];
      axr += v.w * wxr[4 * m + 3];
      axz += v.x * wxz[4 * m + 0];
      axz += v.y * wxz[4 * m + 1];
      axz += v.z * wxz[4 * m + 2];
      axz += v.w * wxz[4 * m + 3];
      axn += v.x * wxn[4 * m + 0];
      axn += v.y * wxn[4 * m + 1];
      axn += v.z * wxn[4 * m + 2];
      axn += v.w * wxn[4 * m + 3];
    }
    // h-dot: 16 k's -> 48 FMA
    #pragma unroll
    for (int m = 0; m < 4; ++m) {
      const float4 v = *(const float4*)(hb + hoff[m]);
      ahr += v.x * whr[4 * m + 0];
      ahr += v.y * whr[4 * m + 1];
      ahr += v.z * whr[4 * m + 2];
      ahr += v.w * whr[4 * m + 3];
      ahz += v.x * whz[4 * m + 0];
      ahz += v.y * whz[4 * m + 1];
      ahz += v.z * whz[4 * m + 2];
      ahz += v.w * whz[4 * m + 3];
      ahn += v.x * whn_[4 * m + 0];
      ahn += v.y * whn_[4 * m + 1];
      ahn += v.z * whn_[4 * m + 2];
      ahn += v.w * whn_[4 * m + 3];
    }

    // 8-lane butterfly: xor1+xor2 via DPP (VALU), xor32 via shfl
    float pr = axr + ahr;
    float pz = axz + ahz;
    float xn = axn;
    float hn = ahn;
    pr = dpp_add_xor1(pr); pr = dpp_add_xor2(pr); pr += __shfl_xor(pr, 32);
    pz = dpp_add_xor1(pz); pz = dpp_add_xor2(pz); pz += __shfl_xor(pz, 32);
    xn = dpp_add_xor1(xn); xn = dpp_add_xor2(xn); xn += __shfl_xor(xn, 32);
    hn = dpp_add_xor1(hn); hn = dpp_add_xor2(hn); hn += __shfl_xor(hn, 32);

    // gates (redundant across the 8 octet lanes; no divergence)
    const float r = 1.0f / (1.0f + __expf(-pr));
    const float z = 1.0f / (1.0f + __expf(-pz));
    const float na = xn + r * hn;
    const float n = 1.0f - 2.0f / (__expf(2.0f * na) + 1.0f);   // tanh
    const float hnew = z * (h_old - n) + n;                     // (1-z)n + z h
    h_old = hnew;

    if (c == 0) {
      h_lds[(t + 1) & 1][g] = hnew;   // 8 consecutive dwords/wave: conflict-free
      *outp = hnew;
    }
    outp += BB * HH;
    if (loader && t + 1 < TT) {
      *(float4*)(x_lds[(t + 1) & 1] + 4 * lidx) = xn4;
    }
    __syncthreads();   // single barrier: h and x double-buffered
  }
}

extern "C" void kernel_launch(void* const* d_in, const int* in_sizes, int n_in,
                              void* d_out, int out_size, void* d_ws, size_t ws_size,
                              hipStream_t stream) {
  const float* x    = (const float*)d_in[0];
  const float* Wi   = (const float*)d_in[1];
  const float* bi   = (const float*)d_in[2];
  const float* Whrz = (const float*)d_in[3];
  const float* Whn  = (const float*)d_in[4];
  const float* bn   = (const float*)d_in[5];
  float* out = (float*)d_out;

  gru_scan_kernel<<<dim3(BB), dim3(NT), 0, stream>>>(
      x, Wi, bi, Whrz, Whn, bn, out);
}

// Round 7
// 1381.022 us; speedup vs baseline: 1.4824x; 1.3657x over previous
//
#include <hip/hip_runtime.h>

#define TT 2048
#define BB 256
#define FF 64
#define HH 128
#define NT 512          // 8 waves; lane = 16*row + 4*p + u; quad-of-rows layout
#define RS (BB * FF / 4)  // x row stride in float4

// pure-VALU butterfly over the 4 lanes spaced 4 apart within a 16-lane row
template <int CTRL>
__device__ __forceinline__ float dpp_add(float v) {
  int r = __builtin_amdgcn_update_dpp(0, __float_as_int(v), CTRL, 0xF, 0xF, true);
  return v + __int_as_float(r);
}
__device__ __forceinline__ float rowquad_sum(float v) {
  v = dpp_add<0x124>(v);  // row_ror:4
  v = dpp_add<0x128>(v);  // row_ror:8
  return v;
}

// In-loop pins: an asm that reads+writes each weight every iteration makes
// reload-from-memory an ILLEGAL materialization -> true register residency.
#define PINS()                                                              \
  do {                                                                      \
    _Pragma("unroll") for (int _k = 0; _k < 32; ++_k) {                     \
      asm volatile("" : "+v"(whr[_k]), "+v"(whz[_k]), "+v"(whn_[_k]));      \
    }                                                                       \
    _Pragma("unroll") for (int _k = 0; _k < 16; ++_k) {                     \
      asm volatile("" : "+v"(wxr[_k]), "+v"(wxz[_k]), "+v"(wxn[_k]));       \
    }                                                                       \
  } while (0)

__global__ void __launch_bounds__(NT)
__attribute__((amdgpu_waves_per_eu(2, 2)))
gru_scan_kernel(const float* __restrict__ x,     // [T,B,F]
                const float* __restrict__ Wi,    // [F,3H] r|z|n
                const float* __restrict__ bi,    // [3H]
                const float* __restrict__ Whrz,  // [H,2H] r|z
                const float* __restrict__ Whn,   // [H,H]
                const float* __restrict__ bn,    // [H]
                float* __restrict__ out)         // [T,B,H]
{
  const int b    = blockIdx.x;
  const int tid  = threadIdx.x;
  const int w    = tid >> 6;        // wave 0..7
  const int lane = tid & 63;
  const int r16  = (lane >> 4) & 3; // 16-lane row within wave
  const int s    = lane & 15;
  const int p    = s >> 2;          // k-part 0..3 (lanes spaced 4 in a row)
  const int u    = s & 3;
  const int g    = w * 16 + r16 * 4 + u;   // hidden unit 0..127

  __shared__ __align__(16) float h_lds[2][HH];
  __shared__ __align__(16) float x_lds[4][FF];   // 4-deep ring

  // bank-disjoint chunk schedules (verified: 4 p-addresses hit 4 disjoint
  // bank quads for every read slot m)
  int hoff[8], xoff[4];
  #pragma unroll
  for (int m = 0; m < 8; ++m) hoff[m] = 32 * p + 4 * ((m + 2 * p) & 7);
  #pragma unroll
  for (int m = 0; m < 4; ++m) xoff[m] = 16 * p + 4 * ((m + p) & 3);

  // ---- stationary weights: 96 h + 48 x = 144 floats/thread ----
  float whr[32], whz[32], whn_[32];
  float wxr[16], wxz[16], wxn[16];
  #pragma unroll
  for (int m = 0; m < 8; ++m) {
    #pragma unroll
    for (int e = 0; e < 4; ++e) {
      const int k = hoff[m] + e;                    // 0..127
      whr[4 * m + e]  = Whrz[(size_t)k * 256 + g];
      whz[4 * m + e]  = Whrz[(size_t)k * 256 + 128 + g];
      whn_[4 * m + e] = Whn[(size_t)k * 128 + g];
    }
  }
  #pragma unroll
  for (int m = 0; m < 4; ++m) {
    #pragma unroll
    for (int e = 0; e < 4; ++e) {
      const int k = xoff[m] + e;                    // 0..63
      wxr[4 * m + e] = Wi[(size_t)k * 384 + g];
      wxz[4 * m + e] = Wi[(size_t)k * 384 + 128 + g];
      wxn[4 * m + e] = Wi[(size_t)k * 384 + 256 + g];
    }
  }
  const float b_r  = (p == 0) ? bi[g]       : 0.0f;
  const float b_z  = (p == 0) ? bi[128 + g] : 0.0f;
  const float b_xn = (p == 0) ? bi[256 + g] : 0.0f;
  const float b_hn = (p == 0) ? bn[g]       : 0.0f;

  // ---- init: h=0, x[0] -> slot 0, prefetch x[1..4] into registers ----
  if (tid < HH) h_lds[0][tid] = 0.0f;
  if (tid < 16) {
    ((float4*)x_lds[0])[tid] = ((const float4*)(x + (size_t)b * FF))[tid];
  }
  const bool loader = (tid >= NT - 16);   // wave 7, lanes 48..63
  const int  lidx   = tid & 15;
  const float4* xsrc = (const float4*)(x + ((size_t)BB + b) * FF) + lidx;
  float4 xv0, xv1, xv2, xv3;
  if (loader) {
    xv0 = xsrc[0 * (size_t)RS];
    xv1 = xsrc[1 * (size_t)RS];
    xv2 = xsrc[2 * (size_t)RS];
    xv3 = xsrc[3 * (size_t)RS];
    xsrc += 4 * (size_t)RS;               // now points at row 5
  }
  float* outp = out + (size_t)b * HH + g;
  float h_old = 0.0f;
  __syncthreads();

#define STEP(P, XV)                                                         \
  {                                                                         \
    const int t_ = tbase + (P);                                             \
    PINS();                                                                 \
    if (loader) {                                                           \
      *(float4*)&x_lds[((P) + 1) & 3][4 * lidx] = XV;  /* x[t+1] */         \
      if (t_ + 5 < TT) { XV = *xsrc; xsrc += RS; }     /* x[t+5] */         \
    }                                                                       \
    const float* xb = x_lds[(P) & 3];                                       \
    const float* hb = h_lds[(P) & 1];                                       \
    float axr = b_r, axz = b_z, axn = b_xn;                                 \
    float ahr = 0.0f, ahz = 0.0f, ahn = b_hn;                               \
    _Pragma("unroll")                                                       \
    for (int m = 0; m < 4; ++m) {                                           \
      const float4 v = *(const float4*)(xb + xoff[m]);                      \
      axr += v.x * wxr[4 * m + 0]; axr += v.y * wxr[4 * m + 1];             \
      axr += v.z * wxr[4 * m + 2]; axr += v.w * wxr[4 * m + 3];             \
      axz += v.x * wxz[4 * m + 0]; axz += v.y * wxz[4 * m + 1];             \
      axz += v.z * wxz[4 * m + 2]; axz += v.w * wxz[4 * m + 3];             \
      axn += v.x * wxn[4 * m + 0]; axn += v.y * wxn[4 * m + 1];             \
      axn += v.z * wxn[4 * m + 2]; axn += v.w * wxn[4 * m + 3];             \
    }                                                                       \
    _Pragma("unroll")                                                       \
    for (int m = 0; m < 8; ++m) {                                           \
      const float4 v = *(const float4*)(hb + hoff[m]);                      \
      ahr += v.x * whr[4 * m + 0]; ahr += v.y * whr[4 * m + 1];             \
      ahr += v.z * whr[4 * m + 2]; ahr += v.w * whr[4 * m + 3];             \
      ahz += v.x * whz[4 * m + 0]; ahz += v.y * whz[4 * m + 1];             \
      ahz += v.z * whz[4 * m + 2]; ahz += v.w * whz[4 * m + 3];             \
      ahn += v.x * whn_[4 * m + 0]; ahn += v.y * whn_[4 * m + 1];           \
      ahn += v.z * whn_[4 * m + 2]; ahn += v.w * whn_[4 * m + 3];           \
    }                                                                       \
    float pr = rowquad_sum(axr + ahr);                                      \
    float pz = rowquad_sum(axz + ahz);                                      \
    float xnv = rowquad_sum(axn);                                           \
    float hnv = rowquad_sum(ahn);                                           \
    const float rg = 1.0f / (1.0f + __expf(-pr));                           \
    const float zg = 1.0f / (1.0f + __expf(-pz));                           \
    const float na = xnv + rg * hnv;                                        \
    const float ng = 1.0f - 2.0f / (__expf(2.0f * na) + 1.0f);              \
    const float hnew = zg * (h_old - ng) + ng;                              \
    h_old = hnew;                                                           \
    if (p == 0) {                                                           \
      h_lds[((P) + 1) & 1][g] = hnew;                                       \
      *outp = hnew;                                                         \
    }                                                                       \
    outp += BB * HH;                                                        \
    __syncthreads();                                                        \
  }

  for (int tbase = 0; tbase < TT; tbase += 4) {
    STEP(0, xv0)
    STEP(1, xv1)
    STEP(2, xv2)
    STEP(3, xv3)
  }
#undef STEP
}

extern "C" void kernel_launch(void* const* d_in, const int* in_sizes, int n_in,
                              void* d_out, int out_size, void* d_ws, size_t ws_size,
                              hipStream_t stream) {
  const float* x    = (const float*)d_in[0];
  const float* Wi   = (const float*)d_in[1];
  const float* bi   = (const float*)d_in[2];
  const float* Whrz = (const float*)d_in[3];
  const float* Whn  = (const float*)d_in[4];
  const float* bn   = (const float*)d_in[5];
  float* out = (float*)d_out;

  gru_scan_kernel<<<dim3(BB), dim3(NT), 0, stream>>>(
      x, Wi, bi, Whrz, Whn, bn, out);
}

// Round 8
// 1348.165 us; speedup vs baseline: 1.5185x; 1.0244x over previous
//
#include <hip/hip_runtime.h>

#define TT 2048
#define BB 256
#define FF 64
#define HH 128
#define NT 512            // 8 waves; lane = 16*row + 4*p + u
#define RS (BB * FF / 4)  // x row stride in float4

typedef _Float16 h2v __attribute__((ext_vector_type(2)));
typedef _Float16 h4v __attribute__((ext_vector_type(4)));
typedef _Float16 h8v __attribute__((ext_vector_type(8)));

__device__ __forceinline__ float fdot2(h2v a, h2v b, float c) {
  return __builtin_amdgcn_fdot2(a, b, c, false);
}
__device__ __forceinline__ int packh2(float a, float b) {
  union { h2v h; int i; } u;
  u.h = h2v{(_Float16)a, (_Float16)b};
  return u.i;
}
__device__ __forceinline__ h2v ash2(int i) { return __builtin_bit_cast(h2v, i); }

// pure-VALU butterfly over the 4 lanes spaced 4 apart within a 16-lane row
template <int CTRL>
__device__ __forceinline__ float dpp_add(float v) {
  int r = __builtin_amdgcn_update_dpp(0, __float_as_int(v), CTRL, 0xF, 0xF, true);
  return v + __int_as_float(r);
}
__device__ __forceinline__ float rowquad_sum(float v) {
  v = dpp_add<0x124>(v);  // row_ror:4
  v = dpp_add<0x128>(v);  // row_ror:8
  return v;
}

// In-loop pins (proven round 7): reload-from-memory becomes illegal, weights
// stay loop-carried in VGPRs. Weights are half2 packed in ints: 72/thread.
#define PINS()                                                             \
  do {                                                                     \
    _Pragma("unroll") for (int _k = 0; _k < 16; ++_k) {                    \
      asm volatile("" : "+v"(whr_i[_k]), "+v"(whz_i[_k]), "+v"(whn_i[_k]));\
    }                                                                      \
    _Pragma("unroll") for (int _k = 0; _k < 8; ++_k) {                     \
      asm volatile("" : "+v"(wxr_i[_k]), "+v"(wxz_i[_k]), "+v"(wxn_i[_k]));\
    }                                                                      \
  } while (0)

__global__ void __launch_bounds__(NT)
__attribute__((amdgpu_waves_per_eu(2, 2)))
gru_scan_kernel(const float* __restrict__ x,     // [T,B,F]
                const float* __restrict__ Wi,    // [F,3H] r|z|n
                const float* __restrict__ bi,    // [3H]
                const float* __restrict__ Whrz,  // [H,2H] r|z
                const float* __restrict__ Whn,   // [H,H]
                const float* __restrict__ bn,    // [H]
                float* __restrict__ out)         // [T,B,H]
{
  const int b    = blockIdx.x;
  const int tid  = threadIdx.x;
  const int w    = tid >> 6;        // wave 0..7
  const int lane = tid & 63;
  const int r16  = (lane >> 4) & 3;
  const int s    = lane & 15;
  const int p    = s >> 2;          // k-part 0..3
  const int u    = s & 3;
  const int g    = w * 16 + r16 * 4 + u;   // hidden unit 0..127

  // f16 operand buffers (matmul inputs only; carried h state stays fp32)
  __shared__ __align__(16) _Float16 h_lds[2][HH];
  __shared__ __align__(16) _Float16 x_lds[4][FF];   // 4-deep ring

  // bank-disjoint chunk schedules (half-element offsets).
  // h: byte=64p+16*sigma, sigma=(m+(p&2))&3 -> p0/p2 and p1/p3 disjoint.
  // x: byte=32p+16m -> the 4 p-ranges are always disjoint.
  int hoff[4], xoff[2];
  #pragma unroll
  for (int m = 0; m < 4; ++m) hoff[m] = 32 * p + 8 * ((m + (p & 2)) & 3);
  #pragma unroll
  for (int m = 0; m < 2; ++m) xoff[m] = 16 * p + 8 * m;

  // ---- stationary weights: (16+8)*3 = 72 half2-in-int per thread ----
  int whr_i[16], whz_i[16], whn_i[16];
  int wxr_i[8], wxz_i[8], wxn_i[8];
  #pragma unroll
  for (int m = 0; m < 4; ++m) {
    #pragma unroll
    for (int e = 0; e < 4; ++e) {
      const int k = hoff[m] + 2 * e;   // k, k+1 in 0..127
      whr_i[4 * m + e]  = packh2(Whrz[(size_t)k * 256 + g],
                                 Whrz[(size_t)(k + 1) * 256 + g]);
      whz_i[4 * m + e]  = packh2(Whrz[(size_t)k * 256 + 128 + g],
                                 Whrz[(size_t)(k + 1) * 256 + 128 + g]);
      whn_i[4 * m + e]  = packh2(Whn[(size_t)k * 128 + g],
                                 Whn[(size_t)(k + 1) * 128 + g]);
    }
  }
  #pragma unroll
  for (int m = 0; m < 2; ++m) {
    #pragma unroll
    for (int e = 0; e < 4; ++e) {
      const int k = xoff[m] + 2 * e;   // k, k+1 in 0..63
      wxr_i[4 * m + e] = packh2(Wi[(size_t)k * 384 + g],
                                Wi[(size_t)(k + 1) * 384 + g]);
      wxz_i[4 * m + e] = packh2(Wi[(size_t)k * 384 + 128 + g],
                                Wi[(size_t)(k + 1) * 384 + 128 + g]);
      wxn_i[4 * m + e] = packh2(Wi[(size_t)k * 384 + 256 + g],
                                Wi[(size_t)(k + 1) * 384 + 256 + g]);
    }
  }
  const float b_r  = (p == 0) ? bi[g]       : 0.0f;
  const float b_z  = (p == 0) ? bi[128 + g] : 0.0f;
  const float b_xn = (p == 0) ? bi[256 + g] : 0.0f;
  const float b_hn = (p == 0) ? bn[g]       : 0.0f;

  // ---- init: h=0, x[0] -> slot 0, prefetch x[1..4] into registers ----
  if (tid < HH) h_lds[0][tid] = (_Float16)0.0f;
  if (tid < 16) {
    const float4 v = ((const float4*)(x + (size_t)b * FF))[tid];
    *(h4v*)&x_lds[0][4 * tid] =
        h4v{(_Float16)v.x, (_Float16)v.y, (_Float16)v.z, (_Float16)v.w};
  }
  const bool loader = (tid >= NT - 16);   // wave 7, lanes 48..63
  const int  lidx   = tid & 15;
  const float4* xsrc = (const float4*)(x + ((size_t)BB + b) * FF) + lidx;
  float4 xv0, xv1, xv2, xv3;
  if (loader) {
    xv0 = xsrc[0 * (size_t)RS];
    xv1 = xsrc[1 * (size_t)RS];
    xv2 = xsrc[2 * (size_t)RS];
    xv3 = xsrc[3 * (size_t)RS];
    xsrc += 4 * (size_t)RS;               // now points at row 5
  }
  float* outp = out + (size_t)b * HH + g;
  float h_old = 0.0f;
  __syncthreads();

#define STEP(P, XV)                                                         \
  {                                                                         \
    const int t_ = tbase + (P);                                             \
    PINS();                                                                 \
    if (loader) {                                                           \
      *(h4v*)&x_lds[((P) + 1) & 3][4 * lidx] =                              \
          h4v{(_Float16)XV.x, (_Float16)XV.y, (_Float16)XV.z,               \
              (_Float16)XV.w};                               /* x[t+1] */   \
      if (t_ + 5 < TT) { XV = *xsrc; xsrc += RS; }           /* x[t+5] */   \
    }                                                                       \
    const _Float16* xb = x_lds[(P) & 3];                                    \
    const _Float16* hb = h_lds[(P) & 1];                                    \
    float axr = b_r, axz = b_z, axn = b_xn;                                 \
    float ahr0 = 0.0f, ahz0 = 0.0f, ahn0 = b_hn;                            \
    float ahr1 = 0.0f, ahz1 = 0.0f, ahn1 = 0.0f;                            \
    _Pragma("unroll")                                                       \
    for (int m = 0; m < 2; ++m) {                                           \
      const h8v v = *(const h8v*)(xb + xoff[m]);                            \
      const h2v v0 = h2v{v.s0, v.s1}, v1 = h2v{v.s2, v.s3};                 \
      const h2v v2 = h2v{v.s4, v.s5}, v3 = h2v{v.s6, v.s7};                 \
      axr = fdot2(v0, ash2(wxr_i[4 * m + 0]), axr);                         \
      axr = fdot2(v1, ash2(wxr_i[4 * m + 1]), axr);                         \
      axr = fdot2(v2, ash2(wxr_i[4 * m + 2]), axr);                         \
      axr = fdot2(v3, ash2(wxr_i[4 * m + 3]), axr);                         \
      axz = fdot2(v0, ash2(wxz_i[4 * m + 0]), axz);                         \
      axz = fdot2(v1, ash2(wxz_i[4 * m + 1]), axz);                         \
      axz = fdot2(v2, ash2(wxz_i[4 * m + 2]), axz);                         \
      axz = fdot2(v3, ash2(wxz_i[4 * m + 3]), axz);                         \
      axn = fdot2(v0, ash2(wxn_i[4 * m + 0]), axn);                         \
      axn = fdot2(v1, ash2(wxn_i[4 * m + 1]), axn);                         \
      axn = fdot2(v2, ash2(wxn_i[4 * m + 2]), axn);                         \
      axn = fdot2(v3, ash2(wxn_i[4 * m + 3]), axn);                         \
    }                                                                       \
    _Pragma("unroll")                                                       \
    for (int m = 0; m < 4; ++m) {                                           \
      const h8v v = *(const h8v*)(hb + hoff[m]);                            \
      const h2v v0 = h2v{v.s0, v.s1}, v1 = h2v{v.s2, v.s3};                 \
      const h2v v2 = h2v{v.s4, v.s5}, v3 = h2v{v.s6, v.s7};                 \
      float& br = (m < 2) ? ahr0 : ahr1;                                    \
      float& bz = (m < 2) ? ahz0 : ahz1;                                    \
      float& bn_ = (m < 2) ? ahn0 : ahn1;                                   \
      br = fdot2(v0, ash2(whr_i[4 * m + 0]), br);                           \
      br = fdot2(v1, ash2(whr_i[4 * m + 1]), br);                           \
      br = fdot2(v2, ash2(whr_i[4 * m + 2]), br);                           \
      br = fdot2(v3, ash2(whr_i[4 * m + 3]), br);                           \
      bz = fdot2(v0, ash2(whz_i[4 * m + 0]), bz);                           \
      bz = fdot2(v1, ash2(whz_i[4 * m + 1]), bz);                           \
      bz = fdot2(v2, ash2(whz_i[4 * m + 2]), bz);                           \
      bz = fdot2(v3, ash2(whz_i[4 * m + 3]), bz);                           \
      bn_ = fdot2(v0, ash2(whn_i[4 * m + 0]), bn_);                         \
      bn_ = fdot2(v1, ash2(whn_i[4 * m + 1]), bn_);                         \
      bn_ = fdot2(v2, ash2(whn_i[4 * m + 2]), bn_);                         \
      bn_ = fdot2(v3, ash2(whn_i[4 * m + 3]), bn_);                         \
    }                                                                       \
    float pr = rowquad_sum(axr + (ahr0 + ahr1));                            \
    float pz = rowquad_sum(axz + (ahz0 + ahz1));                            \
    float xnv = rowquad_sum(axn);                                           \
    float hnv = rowquad_sum(ahn0 + ahn1);                                   \
    const float rg = 1.0f / (1.0f + __expf(-pr));                           \
    const float zg = 1.0f / (1.0f + __expf(-pz));                           \
    const float na = xnv + rg * hnv;                                        \
    const float ng = 1.0f - 2.0f / (__expf(2.0f * na) + 1.0f);              \
    const float hnew = zg * (h_old - ng) + ng;                              \
    h_old = hnew;                                                           \
    if (p == 0) {                                                           \
      h_lds[((P) + 1) & 1][g] = (_Float16)hnew;                             \
      *outp = hnew;                                                         \
    }                                                                       \
    outp += BB * HH;                                                        \
    __syncthreads();                                                        \
  }

  for (int tbase = 0; tbase < TT; tbase += 4) {
    STEP(0, xv0)
    STEP(1, xv1)
    STEP(2, xv2)
    STEP(3, xv3)
  }
#undef STEP
}

extern "C" void kernel_launch(void* const* d_in, const int* in_sizes, int n_in,
                              void* d_out, int out_size, void* d_ws, size_t ws_size,
                              hipStream_t stream) {
  const float* x    = (const float*)d_in[0];
  const float* Wi   = (const float*)d_in[1];
  const float* bi   = (const float*)d_in[2];
  const float* Whrz = (const float*)d_in[3];
  const float* Whn  = (const float*)d_in[4];
  const float* bn   = (const float*)d_in[5];
  float* out = (float*)d_out;

  gru_scan_kernel<<<dim3(BB), dim3(NT), 0, stream>>>(
      x, Wi, bi, Whrz, Whn, bn, out);
}